// Round 9
// baseline (856.350 us; speedup 1.0000x reference)
//
#include <hip/hip_runtime.h>
#include <hip/hip_bf16.h>

// B=2, L=4096, D=512, H=8, Hd=64, causal MHA, outputs (out, attn) fp32.

typedef __attribute__((ext_vector_type(8))) __bf16 bf16x8;
typedef __attribute__((ext_vector_type(4))) __bf16 bf16v4;
typedef __attribute__((ext_vector_type(4))) float f32x4;
typedef __attribute__((ext_vector_type(4))) unsigned short u16x4;

constexpr int LL = 4096;
constexpr int DD = 512;
constexpr int HH = 8;
constexpr int HD = 64;
constexpr int BB = 2;
constexpr int BL = BB * LL;
constexpr size_t OUT_ELEMS = (size_t)BB * LL * DD;
constexpr int CH = 8;                   // 64-col K-tiles per chunk (512 cols)
constexpr int NCHUNK = LL / 64 / CH;    // 8
constexpr int CHUNKS_PER_BH = 288;      // sum_{qb=0..63} (qb/8 + 1)

// triangular chunk-table offset (units of one 64x64 tile = 4096 elems)
static __device__ inline int chunk_off(int qb) {
    const int g = qb >> 3, r = qb & 7;
    return qb + 4 * g * (g - 1) + r * g;
}

static __device__ inline bf16x8 cvt8(const float* p) {
    float4 a = *reinterpret_cast<const float4*>(p);
    float4 b = *reinterpret_cast<const float4*>(p + 4);
    bf16x8 r;
    r[0] = (__bf16)a.x; r[1] = (__bf16)a.y; r[2] = (__bf16)a.z; r[3] = (__bf16)a.w;
    r[4] = (__bf16)b.x; r[5] = (__bf16)b.y; r[6] = (__bf16)b.z; r[7] = (__bf16)b.w;
    return r;
}

// ---------------------------------------------------------------------------
// Kernel 0: fp32 -> bf16 prepack of the three inputs.
// ---------------------------------------------------------------------------
__global__ __launch_bounds__(256) void cvt_kernel(
    const float* __restrict__ q, const float* __restrict__ k,
    const float* __restrict__ v, __bf16* __restrict__ o)
{
    constexpr size_t N = (size_t)BL * DD;
    size_t i = ((size_t)blockIdx.x * 256 + threadIdx.x) * 8;
    const float* src = q; size_t j = i;
    if (i >= 2 * N)      { src = v; j = i - 2 * N; }
    else if (i >= N)     { src = k; j = i - N; }
    *reinterpret_cast<bf16x8*>(&o[i]) = cvt8(&src[j]);
}

// ---------------------------------------------------------------------------
// Kernel Z: zero-fill the strictly-above-diagonal TILE region of attn with
// fully contiguous wave stores (64 lanes x 16B = 1KB/instr).
// grid (16 bh, 63 qb, 4 col-strip), block 256 (4 waves; wave w: rows w::4).
// ---------------------------------------------------------------------------
__global__ __launch_bounds__(256) void zero_kernel(float* __restrict__ attn_out)
{
    const int bh = blockIdx.x;
    const int qb = blockIdx.y;               // 0..62 (qb=63 has no zero tiles)
    const int z  = blockIdx.z;

    const int wv   = threadIdx.x >> 6;
    const int lane = threadIdx.x & 63;

    const int strip = 1024 - (qb + 1) * 16;  // floats per strip (mult of 16)
    const int col0  = (qb + 1) * 64 + z * strip;
    float* base = attn_out + (size_t)bh * LL * LL + (size_t)qb * 64 * LL;

    const f32x4 z4 = {0.f, 0.f, 0.f, 0.f};
    for (int r = wv; r < 64; r += 4) {
        float* row = base + (size_t)r * LL + col0;
        for (int c = lane * 4; c < strip; c += 256)
            *reinterpret_cast<f32x4*>(row + c) = z4;
    }
}

// ---------------------------------------------------------------------------
// Kernel 1: QKV projection from bf16 inputs. y = x @ W.T + b, bf16 out.
// z=0 -> Q [B,H,L,64]; z=1 -> K [B,H,L,64]; z=2 -> V^T [B,H,64,L].
// grid (BL/64, 8, 3), block 256.
// ---------------------------------------------------------------------------
__global__ __launch_bounds__(256) void qkv_kernel(
    const __bf16* __restrict__ Xb,
    const float* __restrict__ Wq, const float* __restrict__ bq,
    const float* __restrict__ Wk, const float* __restrict__ bk,
    const float* __restrict__ Wv, const float* __restrict__ bv,
    __bf16* __restrict__ Qb, __bf16* __restrict__ Kb, __bf16* __restrict__ Vt)
{
    const int z = blockIdx.z;
    const __bf16* x  = Xb + (size_t)z * BL * DD;
    const float* W   = (z == 0) ? Wq : (z == 1) ? Wk : Wv;
    const float* bia = (z == 0) ? bq : (z == 1) ? bk : bv;

    const int wid = threadIdx.x >> 6;
    const int lane = threadIdx.x & 63;
    const int l15 = lane & 15;
    const int lg  = lane >> 4;

    const int r0 = blockIdx.x * 64;
    const int cb = blockIdx.y;
    const int c0 = cb * 64 + wid * 16;

    f32x4 acc[4] = {};
    for (int k0 = 0; k0 < DD; k0 += 32) {
        bf16x8 bfrag = cvt8(&W[(size_t)(c0 + l15) * DD + k0 + lg * 8]);
#pragma unroll
        for (int mt = 0; mt < 4; ++mt) {
            bf16x8 afrag = *reinterpret_cast<const bf16x8*>(
                &x[(size_t)(r0 + mt * 16 + l15) * DD + k0 + lg * 8]);
            acc[mt] = __builtin_amdgcn_mfma_f32_16x16x32_bf16(afrag, bfrag, acc[mt], 0, 0, 0);
        }
    }

    __shared__ __bf16 T[64][72];
    const float bval = bia[c0 + l15];
#pragma unroll
    for (int mt = 0; mt < 4; ++mt)
#pragma unroll
        for (int i = 0; i < 4; ++i) {
            const float val = acc[mt][i] + bval;
            const int row = mt * 16 + lg * 4 + i;
            const int col = wid * 16 + l15;
            if (z == 2) T[col][row] = (__bf16)val;
            else        T[row][col] = (__bf16)val;
        }
    __syncthreads();

    const int tr  = threadIdx.x >> 2;
    const int seg = threadIdx.x & 3;
    uint4 v0 = *reinterpret_cast<const uint4*>(&T[tr][seg * 16]);
    uint4 v1 = *reinterpret_cast<const uint4*>(&T[tr][seg * 16 + 8]);
    const int b  = r0 >> 12;
    const int l0 = r0 & (LL - 1);
    if (z == 2) {
        __bf16* dst = Vt + ((size_t)(b * HH + cb) * HD + tr) * LL + l0 + seg * 16;
        *reinterpret_cast<uint4*>(dst)     = v0;
        *reinterpret_cast<uint4*>(dst + 8) = v1;
    } else {
        __bf16* base = (z == 0) ? Qb : Kb;
        __bf16* dst = base + ((size_t)(b * HH + cb) * LL + l0 + tr) * HD + seg * 16;
        *reinterpret_cast<uint4*>(dst)     = v0;
        *reinterpret_cast<uint4*>(dst + 8) = v1;
    }
}

// ---------------------------------------------------------------------------
// Kernel 2a: chunked row sums, K register double-buffer.
// grid (16 bh, 64 qb, NCHUNK), block 256. Early-exit above diagonal.
// ---------------------------------------------------------------------------
__global__ __launch_bounds__(256, 4) void rowsum_kernel(
    const __bf16* __restrict__ Qb, const __bf16* __restrict__ Kb,
    float* __restrict__ rspart)
{
    const int bh = blockIdx.x;
    const int qb = 63 - blockIdx.y;          // heavy WGs first
    const int ch = blockIdx.z;
    const int kb0 = ch * CH;
    if (kb0 > qb) return;

    const int wv   = threadIdx.x >> 6;
    const int lane = threadIdx.x & 63;
    const int l15  = lane & 15;
    const int lg   = lane >> 4;

    const __bf16* Qh = Qb + (size_t)bh * LL * HD;
    const __bf16* Kh = Kb + (size_t)bh * LL * HD;

    const int q0 = qb * 64 + wv * 16;
    const int qrow = q0 + l15;
    const bf16x8 qf0 = *reinterpret_cast<const bf16x8*>(&Qh[(size_t)qrow * HD + lg * 8]);
    const bf16x8 qf1 = *reinterpret_cast<const bf16x8*>(&Qh[(size_t)qrow * HD + 32 + lg * 8]);
    const float SC = 0.125f * 1.44269504088896f;

    auto loadK = [&](bf16x8 (&kf)[8], int kb) {
        const __bf16* kp = &Kh[((size_t)kb * 64 + l15) * HD + lg * 8];
#pragma unroll
        for (int kt = 0; kt < 4; ++kt) {
            kf[kt * 2]     = *reinterpret_cast<const bf16x8*>(kp + (size_t)kt * 16 * HD);
            kf[kt * 2 + 1] = *reinterpret_cast<const bf16x8*>(kp + (size_t)kt * 16 * HD + 32);
        }
    };

    float rs = 0.f;
    auto body = [&](bf16x8 (&kf)[8], int kb) {
        f32x4 s[4] = {};
#pragma unroll
        for (int kt = 0; kt < 4; ++kt) {
            s[kt] = __builtin_amdgcn_mfma_f32_16x16x32_bf16(kf[kt * 2],     qf0, s[kt], 0, 0, 0);
            s[kt] = __builtin_amdgcn_mfma_f32_16x16x32_bf16(kf[kt * 2 + 1], qf1, s[kt], 0, 0, 0);
        }
        const bool diag = (kb == qb);
#pragma unroll
        for (int kt = 0; kt < 4; ++kt)
#pragma unroll
            for (int i = 0; i < 4; ++i) {
                float e = exp2f(s[kt][i] * SC);
                if (diag && (kb * 64 + kt * 16 + lg * 4 + i) > qrow) e = 0.f;
                rs += e;
            }
    };

    const int kend = (qb < kb0 + CH - 1) ? qb : kb0 + CH - 1;
    {
        bf16x8 kA[8], kB[8];
        int kb = kb0;
        bool useA = true;
        loadK(kA, kb);
        for (; kb <= kend; ++kb) {
            if (useA) { if (kb + 1 <= kend) loadK(kB, kb + 1); body(kA, kb); }
            else      { if (kb + 1 <= kend) loadK(kA, kb + 1); body(kB, kb); }
            useA = !useA;
        }
    }
    rs += __shfl_xor(rs, 16, 64);
    rs += __shfl_xor(rs, 32, 64);
    if (lane < 16)
        rspart[((size_t)bh * LL + qrow) * NCHUNK + ch] = rs;
}

// ---------------------------------------------------------------------------
// Kernel 2b: chunked attn write + partial PV.
// P accumulates in a per-wave LDS buffer over 4 K-tiles; the flush phase then
// stores each row as ONE 1KB-contiguous instruction (64 lanes x 16B), with
// bf16->fp32 expansion in registers. K reg-double-buffered, V at tile top.
// grid (16 bh, 64 qb, NCHUNK), block 256.
// ---------------------------------------------------------------------------
__global__ __launch_bounds__(256, 3) void attn_main_kernel(
    const __bf16* __restrict__ Qb, const __bf16* __restrict__ Kb,
    const __bf16* __restrict__ Vt, const float* __restrict__ rspart,
    __bf16* __restrict__ opart, float* __restrict__ attn_out)
{
    const int bh = blockIdx.x;
    const int qb = 63 - blockIdx.y;
    const int ch = blockIdx.z;
    const int kb0 = ch * CH;
    if (kb0 > qb) return;                    // zero region handled by zero_kernel

    const int wv   = threadIdx.x >> 6;
    const int lane = threadIdx.x & 63;
    const int l15  = lane & 15;
    const int lg   = lane >> 4;

    float* A_out = attn_out + (size_t)bh * LL * LL;
    const int q0 = qb * 64 + wv * 16;
    const int qrow = q0 + l15;

    const __bf16* Qh = Qb + (size_t)bh * LL * HD;
    const __bf16* Kh = Kb + (size_t)bh * LL * HD;
    const __bf16* Vh = Vt + (size_t)bh * HD * LL;

    __shared__ __bf16 Pbuf[4][16][264];      // per-wave 16 rows x 256 cols (+8 pad)

    const bf16x8 qf0 = *reinterpret_cast<const bf16x8*>(&Qh[(size_t)qrow * HD + lg * 8]);
    const bf16x8 qf1 = *reinterpret_cast<const bf16x8*>(&Qh[(size_t)qrow * HD + 32 + lg * 8]);

    float rsv = 0.f;
    const int nc = qb >> 3;
    const float* rp = &rspart[((size_t)bh * LL + qrow) * NCHUNK];
    for (int c = 0; c <= nc; ++c) rsv += rp[c];
    const float llog = -log2f(rsv);
    const float SC = 0.125f * 1.44269504088896f;

    f32x4 oacc[4] = {};

    auto loadK = [&](bf16x8 (&kf)[8], int kb) {
        const __bf16* kp = &Kh[((size_t)kb * 64 + l15) * HD + lg * 8];
#pragma unroll
        for (int kt = 0; kt < 4; ++kt) {
            kf[kt * 2]     = *reinterpret_cast<const bf16x8*>(kp + (size_t)kt * 16 * HD);
            kf[kt * 2 + 1] = *reinterpret_cast<const bf16x8*>(kp + (size_t)kt * 16 * HD + 32);
        }
    };

    // compute one tile into Pbuf columns tt*64.. and accumulate PV
    auto body = [&](bf16x8 (&kf)[8], int kb, int tt) {
        bf16x8 vf[8];
        {
            const __bf16* vp = &Vh[(size_t)l15 * LL + (size_t)kb * 64 + lg * 8];
#pragma unroll
            for (int ht = 0; ht < 4; ++ht) {
                vf[ht * 2]     = *reinterpret_cast<const bf16x8*>(vp + (size_t)ht * 16 * LL);
                vf[ht * 2 + 1] = *reinterpret_cast<const bf16x8*>(vp + (size_t)ht * 16 * LL + 32);
            }
        }
        f32x4 s[4] = {};
#pragma unroll
        for (int kt = 0; kt < 4; ++kt) {
            s[kt] = __builtin_amdgcn_mfma_f32_16x16x32_bf16(kf[kt * 2],     qf0, s[kt], 0, 0, 0);
            s[kt] = __builtin_amdgcn_mfma_f32_16x16x32_bf16(kf[kt * 2 + 1], qf1, s[kt], 0, 0, 0);
        }
        const bool diag = (kb == qb);
#pragma unroll
        for (int kt = 0; kt < 4; ++kt) {
            float e0 = exp2f(fmaf(s[kt][0], SC, llog));
            float e1 = exp2f(fmaf(s[kt][1], SC, llog));
            float e2 = exp2f(fmaf(s[kt][2], SC, llog));
            float e3 = exp2f(fmaf(s[kt][3], SC, llog));
            if (diag) {
                const int kc = kb * 64 + kt * 16 + lg * 4;
                if (kc + 0 > qrow) e0 = 0.f;
                if (kc + 1 > qrow) e1 = 0.f;
                if (kc + 2 > qrow) e2 = 0.f;
                if (kc + 3 > qrow) e3 = 0.f;
            }
            bf16v4 pk;
            pk[0] = (__bf16)e0; pk[1] = (__bf16)e1;
            pk[2] = (__bf16)e2; pk[3] = (__bf16)e3;
            *reinterpret_cast<bf16v4*>(&Pbuf[wv][l15][tt * 64 + kt * 16 + lg * 4]) = pk;
        }
        const bf16x8 pa0 = *reinterpret_cast<const bf16x8*>(&Pbuf[wv][l15][tt * 64 + lg * 8]);
        const bf16x8 pa1 = *reinterpret_cast<const bf16x8*>(&Pbuf[wv][l15][tt * 64 + 32 + lg * 8]);
#pragma unroll
        for (int ht = 0; ht < 4; ++ht) {
            oacc[ht] = __builtin_amdgcn_mfma_f32_16x16x32_bf16(pa0, vf[ht * 2],     oacc[ht], 0, 0, 0);
            oacc[ht] = __builtin_amdgcn_mfma_f32_16x16x32_bf16(pa1, vf[ht * 2 + 1], oacc[ht], 0, 0, 0);
        }
    };

    // flush macro-phase mp (vt valid tiles): per row ONE 1KB-contiguous store
    auto flush = [&](int mp, int vt) {
        if (lane * 4 < vt * 64) {
            const int colbase = kb0 * 64 + mp * 256 + lane * 4;
#pragma unroll
            for (int r = 0; r < 16; ++r) {
                u16x4 u = *reinterpret_cast<const u16x4*>(&Pbuf[wv][r][lane * 4]);
                f32x4 v;
                v[0] = __uint_as_float((unsigned)u[0] << 16);
                v[1] = __uint_as_float((unsigned)u[1] << 16);
                v[2] = __uint_as_float((unsigned)u[2] << 16);
                v[3] = __uint_as_float((unsigned)u[3] << 16);
                *reinterpret_cast<f32x4*>(&A_out[(size_t)(q0 + r) * LL + colbase]) = v;
            }
        }
    };

    const int kend = (qb < kb0 + CH - 1) ? qb : kb0 + CH - 1;
    const int nv = kend - kb0 + 1;           // valid tiles: 1..8
    {
        bf16x8 kA[8], kB[8];
        int kb = kb0;
        bool useA = true;
        loadK(kA, kb);
        for (int mp = 0; mp < 2; ++mp) {
            const int vt = (nv - mp * 4 < 4) ? nv - mp * 4 : 4;
            if (vt <= 0) break;
            for (int tt = 0; tt < vt; ++tt, ++kb) {
                if (useA) { if (kb + 1 <= kend) loadK(kB, kb + 1); body(kA, kb, tt); }
                else      { if (kb + 1 <= kend) loadK(kA, kb + 1); body(kB, kb, tt); }
                useA = !useA;
            }
            flush(mp, vt);
        }
    }

    // O partial -> LDS (reuse Pbuf, wave-private) -> coalesced store
#pragma unroll
    for (int ht = 0; ht < 4; ++ht)
#pragma unroll
        for (int i = 0; i < 4; ++i)
            Pbuf[wv][lg * 4 + i][ht * 16 + l15] = (__bf16)oacc[ht][i];
    const int arow = lane >> 2;
    const int aseg = lane & 3;
    uint4 o0 = *reinterpret_cast<const uint4*>(&Pbuf[wv][arow][aseg * 16]);
    uint4 o1 = *reinterpret_cast<const uint4*>(&Pbuf[wv][arow][aseg * 16 + 8]);
    __bf16* dst = opart
        + ((size_t)(bh * CHUNKS_PER_BH + chunk_off(qb) + ch)) * 4096
        + (wv * 16 + arow) * 64 + aseg * 16;
    *reinterpret_cast<uint4*>(dst)     = o0;
    *reinterpret_cast<uint4*>(dst + 8) = o1;
}

// ---------------------------------------------------------------------------
// Kernel 2c: sum O-partials (<= NCHUNK) -> Ob bf16 [B,L,D]. grid (16, 64).
// ---------------------------------------------------------------------------
__global__ __launch_bounds__(256) void oreduce_kernel(
    const __bf16* __restrict__ opart, __bf16* __restrict__ Ob)
{
    const int bh = blockIdx.x;
    const int qb = blockIdx.y;
    const int nc = qb >> 3;
    const __bf16* src = opart + ((size_t)(bh * CHUNKS_PER_BH + chunk_off(qb))) * 4096;
    const int t = threadIdx.x;

    float acc[16] = {};
    for (int c = 0; c <= nc; ++c) {
        bf16x8 a = *reinterpret_cast<const bf16x8*>(&src[(size_t)c * 4096 + t * 16]);
        bf16x8 b = *reinterpret_cast<const bf16x8*>(&src[(size_t)c * 4096 + t * 16 + 8]);
#pragma unroll
        for (int j = 0; j < 8; ++j) { acc[j] += (float)a[j]; acc[8 + j] += (float)b[j]; }
    }
    bf16x8 r0, r1;
#pragma unroll
    for (int j = 0; j < 8; ++j) { r0[j] = (__bf16)acc[j]; r1[j] = (__bf16)acc[8 + j]; }

    const int qr  = t >> 2;
    const int hd0 = (t & 3) * 16;
    const int b = bh >> 3, h = bh & 7;
    __bf16* dst = Ob + ((size_t)(b * LL + qb * 64 + qr)) * DD + h * HD + hd0;
    *reinterpret_cast<bf16x8*>(dst)     = r0;
    *reinterpret_cast<bf16x8*>(dst + 8) = r1;
}

// ---------------------------------------------------------------------------
// Kernel 3: out = Ob(bf16) @ Wo.T + bo -> fp32. grid (BL/64, 8), block 256.
// ---------------------------------------------------------------------------
__global__ __launch_bounds__(256) void oproj_kernel(
    const __bf16* __restrict__ Ob, const float* __restrict__ Wo,
    const float* __restrict__ bo, float* __restrict__ out)
{
    const int wid = threadIdx.x >> 6;
    const int lane = threadIdx.x & 63;
    const int l15 = lane & 15;
    const int lg  = lane >> 4;

    const int r0 = blockIdx.x * 64;
    const int c0 = blockIdx.y * 64 + wid * 16;

    f32x4 acc[4] = {};
    for (int k0 = 0; k0 < DD; k0 += 32) {
        bf16x8 bfrag = cvt8(&Wo[(size_t)(c0 + l15) * DD + k0 + lg * 8]);
#pragma unroll
        for (int mt = 0; mt < 4; ++mt) {
            bf16x8 afrag = *reinterpret_cast<const bf16x8*>(
                &Ob[(size_t)(r0 + mt * 16 + l15) * DD + k0 + lg * 8]);
            acc[mt] = __builtin_amdgcn_mfma_f32_16x16x32_bf16(afrag, bfrag, acc[mt], 0, 0, 0);
        }
    }
    const float bval = bo[c0 + l15];
#pragma unroll
    for (int mt = 0; mt < 4; ++mt)
#pragma unroll
        for (int i = 0; i < 4; ++i)
            out[(size_t)(r0 + mt * 16 + lg * 4 + i) * DD + c0 + l15] = acc[mt][i] + bval;
}

// ---------------------------------------------------------------------------
extern "C" void kernel_launch(void* const* d_in, const int* in_sizes, int n_in,
                              void* d_out, int out_size, void* d_ws, size_t ws_size,
                              hipStream_t stream) {
    const float* query = (const float*)d_in[0];
    const float* key_t = (const float*)d_in[1];
    const float* value = (const float*)d_in[2];
    const float* Wq = (const float*)d_in[3];
    const float* bq = (const float*)d_in[4];
    const float* Wk = (const float*)d_in[5];
    const float* bk = (const float*)d_in[6];
    const float* Wv = (const float*)d_in[7];
    const float* bv = (const float*)d_in[8];
    const float* Wo = (const float*)d_in[9];
    const float* bo = (const float*)d_in[10];

    float* out  = (float*)d_out;             // [B,L,D]
    float* attn = out + OUT_ELEMS;           // [B,H,L,L]

    char* ws = (char*)d_ws;
    __bf16* Qb     = (__bf16*)(ws);                        //  8.39 MB
    __bf16* Kb     = (__bf16*)(ws +  8388608);             //  8.39 MB
    __bf16* Vt     = (__bf16*)(ws + 16777216);             //  8.39 MB
    __bf16* Ob     = (__bf16*)(ws + 25165824);             //  8.39 MB
    float*  rspart = (float*) (ws + 33554432);             //  2.10 MB
    __bf16* Xb     = (__bf16*)(ws + 35651584);             // 25.2 MB (dead after qkv)
    __bf16* opart  = (__bf16*)(ws + 35651584);             // 37.7 MB (overlaps Xb)

    cvt_kernel<<<dim3(3 * BL * DD / 8 / 256), 256, 0, stream>>>(query, key_t, value, Xb);
    zero_kernel<<<dim3(BB * HH, LL / 64 - 1, 4), 256, 0, stream>>>(attn);
    qkv_kernel<<<dim3(BL / 64, DD / 64, 3), 256, 0, stream>>>(
        Xb, Wq, bq, Wk, bk, Wv, bv, Qb, Kb, Vt);
    rowsum_kernel<<<dim3(BB * HH, LL / 64, NCHUNK), 256, 0, stream>>>(Qb, Kb, rspart);
    attn_main_kernel<<<dim3(BB * HH, LL / 64, NCHUNK), 256, 0, stream>>>(
        Qb, Kb, Vt, rspart, opart, attn);
    oreduce_kernel<<<dim3(BB * HH, LL / 64), 256, 0, stream>>>(opart, Ob);
    oproj_kernel<<<dim3(BL / 64, DD / 64), 256, 0, stream>>>(Ob, Wo, bo, out);
}

// Round 10
// 735.109 us; speedup vs baseline: 1.1649x; 1.1649x over previous
//
#include <hip/hip_runtime.h>
#include <hip/hip_bf16.h>

// B=2, L=4096, D=512, H=8, Hd=64, causal MHA, outputs (out, attn) fp32.

typedef __attribute__((ext_vector_type(8))) __bf16 bf16x8;
typedef __attribute__((ext_vector_type(4))) __bf16 bf16v4;
typedef __attribute__((ext_vector_type(4))) float f32x4;

constexpr int LL = 4096;
constexpr int DD = 512;
constexpr int HH = 8;
constexpr int HD = 64;
constexpr int BB = 2;
constexpr int BL = BB * LL;
constexpr size_t OUT_ELEMS = (size_t)BB * LL * DD;

static __device__ inline bf16x8 cvt8(const float* p) {
    float4 a = *reinterpret_cast<const float4*>(p);
    float4 b = *reinterpret_cast<const float4*>(p + 4);
    bf16x8 r;
    r[0] = (__bf16)a.x; r[1] = (__bf16)a.y; r[2] = (__bf16)a.z; r[3] = (__bf16)a.w;
    r[4] = (__bf16)b.x; r[5] = (__bf16)b.y; r[6] = (__bf16)b.z; r[7] = (__bf16)b.w;
    return r;
}

// ---------------------------------------------------------------------------
// Kernel 0: fp32 -> bf16 prepack of the three inputs.
// ---------------------------------------------------------------------------
__global__ __launch_bounds__(256) void cvt_kernel(
    const float* __restrict__ q, const float* __restrict__ k,
    const float* __restrict__ v, __bf16* __restrict__ o)
{
    constexpr size_t N = (size_t)BL * DD;
    size_t i = ((size_t)blockIdx.x * 256 + threadIdx.x) * 8;
    const float* src = q; size_t j = i;
    if (i >= 2 * N)      { src = v; j = i - 2 * N; }
    else if (i >= N)     { src = k; j = i - N; }
    *reinterpret_cast<bf16x8*>(&o[i]) = cvt8(&src[j]);
}

// ---------------------------------------------------------------------------
// Kernel 1: QKV projection from bf16 inputs. y = x @ W.T + b, bf16 out.
// z=0 -> Q [B,H,L,64]; z=1 -> K [B,H,L,64]; z=2 -> V^T [B,H,64,L].
// grid (BL/64, 8, 3), block 256.
// ---------------------------------------------------------------------------
__global__ __launch_bounds__(256) void qkv_kernel(
    const __bf16* __restrict__ Xb,
    const float* __restrict__ Wq, const float* __restrict__ bq,
    const float* __restrict__ Wk, const float* __restrict__ bk,
    const float* __restrict__ Wv, const float* __restrict__ bv,
    __bf16* __restrict__ Qb, __bf16* __restrict__ Kb, __bf16* __restrict__ Vt)
{
    const int z = blockIdx.z;
    const __bf16* x  = Xb + (size_t)z * BL * DD;
    const float* W   = (z == 0) ? Wq : (z == 1) ? Wk : Wv;
    const float* bia = (z == 0) ? bq : (z == 1) ? bk : bv;

    const int wid = threadIdx.x >> 6;
    const int lane = threadIdx.x & 63;
    const int l15 = lane & 15;
    const int lg  = lane >> 4;

    const int r0 = blockIdx.x * 64;
    const int cb = blockIdx.y;
    const int c0 = cb * 64 + wid * 16;

    f32x4 acc[4] = {};
    for (int k0 = 0; k0 < DD; k0 += 32) {
        bf16x8 bfrag = cvt8(&W[(size_t)(c0 + l15) * DD + k0 + lg * 8]);
#pragma unroll
        for (int mt = 0; mt < 4; ++mt) {
            bf16x8 afrag = *reinterpret_cast<const bf16x8*>(
                &x[(size_t)(r0 + mt * 16 + l15) * DD + k0 + lg * 8]);
            acc[mt] = __builtin_amdgcn_mfma_f32_16x16x32_bf16(afrag, bfrag, acc[mt], 0, 0, 0);
        }
    }

    __shared__ __bf16 T[64][72];
    const float bval = bia[c0 + l15];
#pragma unroll
    for (int mt = 0; mt < 4; ++mt)
#pragma unroll
        for (int i = 0; i < 4; ++i) {
            const float val = acc[mt][i] + bval;
            const int row = mt * 16 + lg * 4 + i;
            const int col = wid * 16 + l15;
            if (z == 2) T[col][row] = (__bf16)val;
            else        T[row][col] = (__bf16)val;
        }
    __syncthreads();

    const int tr  = threadIdx.x >> 2;
    const int seg = threadIdx.x & 3;
    uint4 v0 = *reinterpret_cast<const uint4*>(&T[tr][seg * 16]);
    uint4 v1 = *reinterpret_cast<const uint4*>(&T[tr][seg * 16 + 8]);
    const int b  = r0 >> 12;
    const int l0 = r0 & (LL - 1);
    if (z == 2) {
        __bf16* dst = Vt + ((size_t)(b * HH + cb) * HD + tr) * LL + l0 + seg * 16;
        *reinterpret_cast<uint4*>(dst)     = v0;
        *reinterpret_cast<uint4*>(dst + 8) = v1;
    } else {
        __bf16* base = (z == 0) ? Qb : Kb;
        __bf16* dst = base + ((size_t)(b * HH + cb) * LL + l0 + tr) * HD + seg * 16;
        *reinterpret_cast<uint4*>(dst)     = v0;
        *reinterpret_cast<uint4*>(dst + 8) = v1;
    }
}

// ---------------------------------------------------------------------------
// Kernel 2: FUSED causal attention. One WG per (bh, qb) 64-row block.
// Order: (a) zero-fill above-diagonal (stores drain under later compute),
// (b) pass 1: swapped QK (mfma(K,Q)) + exp -> row sums (2 shfl reduce),
// (c) pass 2: recompute QK, normalized P, direct fp32 attn store, PV via
// wave-private LDS P tile, (d) O epilogue -> Ob bf16.
// grid (16 bh, 64 qb-desc), block 256 (wave w owns rows w*16..+15).
// ---------------------------------------------------------------------------
__global__ __launch_bounds__(256) void attn_fused_kernel(
    const __bf16* __restrict__ Qb, const __bf16* __restrict__ Kb,
    const __bf16* __restrict__ Vt, __bf16* __restrict__ Ob,
    float* __restrict__ attn_out)
{
    const int bh = blockIdx.x;
    const int qb = 63 - blockIdx.y;          // heavy WGs dispatch first

    const int wv   = threadIdx.x >> 6;
    const int lane = threadIdx.x & 63;
    const int l15  = lane & 15;
    const int lg   = lane >> 4;

    float* A_out = attn_out + (size_t)bh * LL * LL;
    const int q0 = qb * 64 + wv * 16;
    const int qrow = q0 + l15;

    // ---- (a) zero-fill this wave's 16 rows, cols (qb+1)*64..4095 ----
    // 64 lanes x 16B = 1KB contiguous per instruction; fire-and-forget.
    {
        const f32x4 z4 = {0.f, 0.f, 0.f, 0.f};
        const int c0 = (qb + 1) * 64;
#pragma unroll 1
        for (int r = 0; r < 16; ++r) {
            float* row = A_out + (size_t)(q0 + r) * LL;
            for (int c = c0 + lane * 4; c < LL; c += 256)
                *reinterpret_cast<f32x4*>(row + c) = z4;
        }
    }

    const __bf16* Qh = Qb + (size_t)bh * LL * HD;
    const __bf16* Kh = Kb + (size_t)bh * LL * HD;
    const __bf16* Vh = Vt + (size_t)bh * HD * LL;

    __shared__ __bf16 P[4][16][72];          // wave-private P tile

    const bf16x8 qf0 = *reinterpret_cast<const bf16x8*>(&Qh[(size_t)qrow * HD + lg * 8]);
    const bf16x8 qf1 = *reinterpret_cast<const bf16x8*>(&Qh[(size_t)qrow * HD + 32 + lg * 8]);
    const float SC = 0.125f * 1.44269504088896f;   // scale * log2(e)

    // ---- (b) pass 1: row sums ----
    float rs = 0.f;
    for (int kb = 0; kb <= qb; ++kb) {
        const __bf16* kp = &Kh[((size_t)kb * 64 + l15) * HD + lg * 8];
        f32x4 s[4] = {};
#pragma unroll
        for (int kt = 0; kt < 4; ++kt) {
            bf16x8 k0 = *reinterpret_cast<const bf16x8*>(kp + (size_t)kt * 16 * HD);
            bf16x8 k1 = *reinterpret_cast<const bf16x8*>(kp + (size_t)kt * 16 * HD + 32);
            s[kt] = __builtin_amdgcn_mfma_f32_16x16x32_bf16(k0, qf0, s[kt], 0, 0, 0);
            s[kt] = __builtin_amdgcn_mfma_f32_16x16x32_bf16(k1, qf1, s[kt], 0, 0, 0);
        }
        const bool diag = (kb == qb);
#pragma unroll
        for (int kt = 0; kt < 4; ++kt)
#pragma unroll
            for (int i = 0; i < 4; ++i) {
                float e = exp2f(s[kt][i] * SC);
                if (diag && (kb * 64 + kt * 16 + lg * 4 + i) > qrow) e = 0.f;
                rs += e;
            }
    }
    rs += __shfl_xor(rs, 16, 64);
    rs += __shfl_xor(rs, 32, 64);
    const float llog = -log2f(rs);

    // ---- (c) pass 2: attn write + PV ----
    f32x4 oacc[4] = {};
    for (int kb = 0; kb <= qb; ++kb) {
        const __bf16* kp = &Kh[((size_t)kb * 64 + l15) * HD + lg * 8];
        const __bf16* vp = &Vh[(size_t)l15 * LL + (size_t)kb * 64 + lg * 8];
        // V loads issue first; consumed after the P chain
        bf16x8 vf0 = *reinterpret_cast<const bf16x8*>(vp + (size_t)0 * 16 * LL);
        bf16x8 vf1 = *reinterpret_cast<const bf16x8*>(vp + (size_t)0 * 16 * LL + 32);
        bf16x8 vf2 = *reinterpret_cast<const bf16x8*>(vp + (size_t)1 * 16 * LL);
        bf16x8 vf3 = *reinterpret_cast<const bf16x8*>(vp + (size_t)1 * 16 * LL + 32);
        bf16x8 vf4 = *reinterpret_cast<const bf16x8*>(vp + (size_t)2 * 16 * LL);
        bf16x8 vf5 = *reinterpret_cast<const bf16x8*>(vp + (size_t)2 * 16 * LL + 32);
        bf16x8 vf6 = *reinterpret_cast<const bf16x8*>(vp + (size_t)3 * 16 * LL);
        bf16x8 vf7 = *reinterpret_cast<const bf16x8*>(vp + (size_t)3 * 16 * LL + 32);

        f32x4 s[4] = {};
#pragma unroll
        for (int kt = 0; kt < 4; ++kt) {
            bf16x8 k0 = *reinterpret_cast<const bf16x8*>(kp + (size_t)kt * 16 * HD);
            bf16x8 k1 = *reinterpret_cast<const bf16x8*>(kp + (size_t)kt * 16 * HD + 32);
            s[kt] = __builtin_amdgcn_mfma_f32_16x16x32_bf16(k0, qf0, s[kt], 0, 0, 0);
            s[kt] = __builtin_amdgcn_mfma_f32_16x16x32_bf16(k1, qf1, s[kt], 0, 0, 0);
        }
        const bool diag = (kb == qb);
#pragma unroll
        for (int kt = 0; kt < 4; ++kt) {
            float e0 = exp2f(fmaf(s[kt][0], SC, llog));
            float e1 = exp2f(fmaf(s[kt][1], SC, llog));
            float e2 = exp2f(fmaf(s[kt][2], SC, llog));
            float e3 = exp2f(fmaf(s[kt][3], SC, llog));
            if (diag) {
                const int kc = kb * 64 + kt * 16 + lg * 4;
                if (kc + 0 > qrow) e0 = 0.f;
                if (kc + 1 > qrow) e1 = 0.f;
                if (kc + 2 > qrow) e2 = 0.f;
                if (kc + 3 > qrow) e3 = 0.f;
            }
            // direct fp32 attn store (lane-local row, 16B per lane)
            f32x4 ev = {e0, e1, e2, e3};
            *reinterpret_cast<f32x4*>(
                &A_out[(size_t)qrow * LL + kb * 64 + kt * 16 + lg * 4]) = ev;
            // bf16 pack for PV
            bf16v4 pk;
            pk[0] = (__bf16)e0; pk[1] = (__bf16)e1;
            pk[2] = (__bf16)e2; pk[3] = (__bf16)e3;
            *reinterpret_cast<bf16v4*>(&P[wv][l15][kt * 16 + lg * 4]) = pk;
        }
        const bf16x8 pa0 = *reinterpret_cast<const bf16x8*>(&P[wv][l15][lg * 8]);
        const bf16x8 pa1 = *reinterpret_cast<const bf16x8*>(&P[wv][l15][32 + lg * 8]);
        oacc[0] = __builtin_amdgcn_mfma_f32_16x16x32_bf16(pa0, vf0, oacc[0], 0, 0, 0);
        oacc[0] = __builtin_amdgcn_mfma_f32_16x16x32_bf16(pa1, vf1, oacc[0], 0, 0, 0);
        oacc[1] = __builtin_amdgcn_mfma_f32_16x16x32_bf16(pa0, vf2, oacc[1], 0, 0, 0);
        oacc[1] = __builtin_amdgcn_mfma_f32_16x16x32_bf16(pa1, vf3, oacc[1], 0, 0, 0);
        oacc[2] = __builtin_amdgcn_mfma_f32_16x16x32_bf16(pa0, vf4, oacc[2], 0, 0, 0);
        oacc[2] = __builtin_amdgcn_mfma_f32_16x16x32_bf16(pa1, vf5, oacc[2], 0, 0, 0);
        oacc[3] = __builtin_amdgcn_mfma_f32_16x16x32_bf16(pa0, vf6, oacc[3], 0, 0, 0);
        oacc[3] = __builtin_amdgcn_mfma_f32_16x16x32_bf16(pa1, vf7, oacc[3], 0, 0, 0);
    }

    // ---- (d) O epilogue -> Ob bf16 (LDS transpose, wave-private) ----
#pragma unroll
    for (int ht = 0; ht < 4; ++ht)
#pragma unroll
        for (int i = 0; i < 4; ++i)
            P[wv][lg * 4 + i][ht * 16 + l15] = (__bf16)oacc[ht][i];
    const int arow = lane >> 2;
    const int aseg = lane & 3;
    uint4 o0 = *reinterpret_cast<const uint4*>(&P[wv][arow][aseg * 16]);
    uint4 o1 = *reinterpret_cast<const uint4*>(&P[wv][arow][aseg * 16 + 8]);
    const int b = bh >> 3, h = bh & 7;
    __bf16* dst = Ob + ((size_t)(b * LL + q0 + arow)) * DD + h * HD + aseg * 16;
    *reinterpret_cast<uint4*>(dst)     = o0;
    *reinterpret_cast<uint4*>(dst + 8) = o1;
}

// ---------------------------------------------------------------------------
// Kernel 3: out = Ob(bf16) @ Wo.T + bo -> fp32. grid (BL/64, 8), block 256.
// ---------------------------------------------------------------------------
__global__ __launch_bounds__(256) void oproj_kernel(
    const __bf16* __restrict__ Ob, const float* __restrict__ Wo,
    const float* __restrict__ bo, float* __restrict__ out)
{
    const int wid = threadIdx.x >> 6;
    const int lane = threadIdx.x & 63;
    const int l15 = lane & 15;
    const int lg  = lane >> 4;

    const int r0 = blockIdx.x * 64;
    const int c0 = blockIdx.y * 64 + wid * 16;

    f32x4 acc[4] = {};
    for (int k0 = 0; k0 < DD; k0 += 32) {
        bf16x8 bfrag = cvt8(&Wo[(size_t)(c0 + l15) * DD + k0 + lg * 8]);
#pragma unroll
        for (int mt = 0; mt < 4; ++mt) {
            bf16x8 afrag = *reinterpret_cast<const bf16x8*>(
                &Ob[(size_t)(r0 + mt * 16 + l15) * DD + k0 + lg * 8]);
            acc[mt] = __builtin_amdgcn_mfma_f32_16x16x32_bf16(afrag, bfrag, acc[mt], 0, 0, 0);
        }
    }
    const float bval = bo[c0 + l15];
#pragma unroll
    for (int mt = 0; mt < 4; ++mt)
#pragma unroll
        for (int i = 0; i < 4; ++i)
            out[(size_t)(r0 + mt * 16 + lg * 4 + i) * DD + c0 + l15] = acc[mt][i] + bval;
}

// ---------------------------------------------------------------------------
extern "C" void kernel_launch(void* const* d_in, const int* in_sizes, int n_in,
                              void* d_out, int out_size, void* d_ws, size_t ws_size,
                              hipStream_t stream) {
    const float* query = (const float*)d_in[0];
    const float* key_t = (const float*)d_in[1];
    const float* value = (const float*)d_in[2];
    const float* Wq = (const float*)d_in[3];
    const float* bq = (const float*)d_in[4];
    const float* Wk = (const float*)d_in[5];
    const float* bk = (const float*)d_in[6];
    const float* Wv = (const float*)d_in[7];
    const float* bv = (const float*)d_in[8];
    const float* Wo = (const float*)d_in[9];
    const float* bo = (const float*)d_in[10];

    float* out  = (float*)d_out;             // [B,L,D]
    float* attn = out + OUT_ELEMS;           // [B,H,L,L]

    char* ws = (char*)d_ws;
    __bf16* Qb = (__bf16*)(ws);                        //  8.39 MB
    __bf16* Kb = (__bf16*)(ws +  8388608);             //  8.39 MB
    __bf16* Vt = (__bf16*)(ws + 16777216);             //  8.39 MB
    __bf16* Ob = (__bf16*)(ws + 25165824);             //  8.39 MB
    __bf16* Xb = (__bf16*)(ws + 33554432);             // 25.2 MB

    cvt_kernel<<<dim3(3 * BL * DD / 8 / 256), 256, 0, stream>>>(query, key_t, value, Xb);
    qkv_kernel<<<dim3(BL / 64, DD / 64, 3), 256, 0, stream>>>(
        Xb, Wq, bq, Wk, bk, Wv, bv, Qb, Kb, Vt);
    attn_fused_kernel<<<dim3(BB * HH, LL / 64), 256, 0, stream>>>(Qb, Kb, Vt, Ob, attn);
    oproj_kernel<<<dim3(BL / 64, DD / 64), 256, 0, stream>>>(Ob, Wo, bo, out);
}